// Round 1
// baseline (292.167 us; speedup 1.0000x reference)
//
#include <hip/hip_runtime.h>
#include <hip/hip_bf16.h>
#include <cstdint>

// Problem constants: B=4, S=2048, D=1024, H=16, HD=64
static constexpr int Bq  = 4;
static constexpr int Sq  = 2048;
static constexpr int Dq  = 1024;
static constexpr int Hq  = 16;
static constexpr int HDq = 64;
static constexpr int ROWS = Bq * Sq;        // 8192
static constexpr int QKV_N = 3 * Dq;        // 3072

typedef __bf16 bf16x8 __attribute__((ext_vector_type(8)));
typedef __bf16 bf16x4 __attribute__((ext_vector_type(4)));
typedef __bf16 bf16x2 __attribute__((ext_vector_type(2)));
typedef float  floatx4 __attribute__((ext_vector_type(4)));
typedef float  floatx16 __attribute__((ext_vector_type(16)));
typedef unsigned int uintx4 __attribute__((ext_vector_type(4)));

#define MFMA16(a, b, c) __builtin_amdgcn_mfma_f32_16x16x32_bf16((a), (b), (c), 0, 0, 0)
#define MFMA32(a, b, c) __builtin_amdgcn_mfma_f32_32x32x16_bf16((a), (b), (c), 0, 0, 0)

// 0.125 (1/sqrt(HD)) * log2(e): folded into q so softmax uses exp2 directly.
#define QSCALE 0.18033688011112042f

// Async global->LDS 16B copy (global_load_lds_dwordx4).
__device__ __forceinline__ void async16(const void* g, void* l) {
    __builtin_amdgcn_global_load_lds(
        (const __attribute__((address_space(1))) uint32_t*)g,
        (__attribute__((address_space(3))) uint32_t*)l, 16, 0, 0);
}

// ---------------------------------------------------------------------------
// fp32 -> bf16 elementwise convert, 4 elems/thread
__global__ __launch_bounds__(256) void cvt4_kernel(const float4* __restrict__ in,
                                                   bf16x4* __restrict__ out, int n4) {
    int i = blockIdx.x * 256 + threadIdx.x;
    if (i < n4) {
        float4 v = in[i];
        bf16x4 o;
        o[0] = (__bf16)v.x; o[1] = (__bf16)v.y; o[2] = (__bf16)v.z; o[3] = (__bf16)v.w;
        out[i] = o;
    }
}

// fp32 [K,N] -> bf16 transposed [N,K], LDS-tiled 32x32 for coalescing
__global__ __launch_bounds__(256) void tcvt_kernel(const float* __restrict__ in,
                                                   __bf16* __restrict__ out, int K, int N) {
    __shared__ float t[32][33];
    int n0 = blockIdx.x * 32, k0 = blockIdx.y * 32;
    int c = threadIdx.x & 31, r0 = threadIdx.x >> 5;
#pragma unroll
    for (int rr = 0; rr < 32; rr += 8)
        t[r0 + rr][c] = in[(size_t)(k0 + r0 + rr) * N + n0 + c];
    __syncthreads();
#pragma unroll
    for (int rr = 0; rr < 32; rr += 8)
        out[(size_t)(n0 + r0 + rr) * K + k0 + c] = (__bf16)t[c][r0 + rr];
}

// ---------------------------------------------------------------------------
// C[M,N] = A[M,K] @ BT[N,K]^T + bias[N]  (m97-ladder structure).
// MODE 1: f32 C out.  MODE 2 (QKV): q-chunks scaled by QSCALE -> bf16 C;
// k-chunks -> bf16 C; v-chunks -> transposed Vt[b][h][d][s].
template <int MODE>
__global__ __launch_bounds__(256) void gemm_bt_kernel(const __bf16* __restrict__ A,
                                                      const __bf16* __restrict__ BT,
                                                      const float* __restrict__ bias,
                                                      void* __restrict__ Cout,
                                                      __bf16* __restrict__ Vt,
                                                      int M, int N, int K) {
    __shared__ __bf16 As[128 * 32];
    __shared__ __bf16 Bs[128 * 32];

    const int t = threadIdx.x;
    const int lane = t & 63;
    const int wave = t >> 6;
    const int wm = wave & 1, wn = wave >> 1;
    const int l15 = lane & 15;
    const int kg = (lane >> 4) * 8;

    const int m0 = blockIdx.y * 128;
    const int n0 = blockIdx.x * 128;

    const int srow = t >> 2;
    const int scol = (t & 3) * 8;
    const __bf16* ag = A  + (size_t)(m0 + srow) * K + scol;
    const __bf16* bg = BT + (size_t)(n0 + srow) * K + scol;
    __bf16* al = As + t * 8;
    __bf16* bl = Bs + t * 8;

    floatx4 acc[4][4] = {};

    for (int k0 = 0; k0 < K; k0 += 32) {
        __syncthreads();
        async16(ag + k0,                    al);
        async16(ag + (size_t)64 * K + k0,   al + 2048);
        async16(bg + k0,                    bl);
        async16(bg + (size_t)64 * K + k0,   bl + 2048);
        __syncthreads();

        bf16x8 af[4], bfr[4];
#pragma unroll
        for (int mi = 0; mi < 4; ++mi)
            af[mi] = *(const bf16x8*)(As + (wm * 64 + mi * 16 + l15) * 32 + kg);
#pragma unroll
        for (int ni = 0; ni < 4; ++ni)
            bfr[ni] = *(const bf16x8*)(Bs + (wn * 64 + ni * 16 + l15) * 32 + kg);
#pragma unroll
        for (int mi = 0; mi < 4; ++mi)
#pragma unroll
            for (int ni = 0; ni < 4; ++ni)
                acc[mi][ni] = MFMA16(af[mi], bfr[ni], acc[mi][ni]);
    }

    // C/D layout: col = lane&15, row = (lane>>4)*4 + reg   [verified m89/m91]
    const int r0 = (lane >> 4) * 4;
    const int wn0 = n0 + wn * 64;

    if (MODE == 2 && (wn0 % 192) == 128) {
        // v-chunk -> Vt[b][h][d][s]; lane's 4 consecutive rows = 8B store
#pragma unroll
        for (int ni = 0; ni < 4; ++ni) {
            int col = wn0 + ni * 16 + l15;
            float bv = bias[col];
            int h = col / 192;
            int d = col - h * 192 - 128;
#pragma unroll
            for (int mi = 0; mi < 4; ++mi) {
                int row = m0 + wm * 64 + mi * 16 + r0;
                int b = row >> 11, s = row & 2047;
                bf16x4 vv;
#pragma unroll
                for (int i = 0; i < 4; ++i) vv[i] = (__bf16)(acc[mi][ni][i] + bv);
                *(bf16x4*)(Vt + ((size_t)(b * Hq + h) * HDq + d) * Sq + s) = vv;
            }
        }
    } else {
        // wave-uniform q-scale for MODE 2 q-chunks (wn0%192==0)
        const float sc = (MODE == 2 && (wn0 % 192) == 0) ? QSCALE : 1.0f;
#pragma unroll
        for (int ni = 0; ni < 4; ++ni) {
            int col = wn0 + ni * 16 + l15;
            float bv = bias[col];
#pragma unroll
            for (int mi = 0; mi < 4; ++mi) {
#pragma unroll
                for (int i = 0; i < 4; ++i) {
                    int row = m0 + wm * 64 + mi * 16 + r0 + i;
                    float v = (acc[mi][ni][i] + bv) * sc;
                    size_t off = (size_t)row * N + col;
                    if (MODE == 1) ((float*)Cout)[off] = v;
                    else           ((__bf16*)Cout)[off] = (__bf16)v;
                }
            }
        }
    }
}

// ---------------------------------------------------------------------------
// Flash attention, 32x32-MFMA transposed compute (S^T = K Q^T, O^T = V^T P^T),
// max-free softmax (q pre-scaled by 0.125*log2e -> p = exp2(s)).
//
// Block = one (b,h) x 128 q rows; 4 waves; wave owns 32 q rows (wave*32).
// Grid is bh-major: gridDim.x = 64 (= 0 mod 8), so all 16 q-blocks of a
// (b,h) land on the same XCD -> K/V L2 residency (T1).
//
// S^T 32x32 C-layout: col=q(lane&31), row=key=(reg&3)+8*(reg>>2)+4*(lane>>5).
// P regrouping for PV's B-frag (k=(lane>>5)*8+j) is exactly 2
// permlane32_swap per 16-key slice (T12, HK recipe: swap(W[i],W[i+2])) --
// no P round-trip through LDS at all.
//
// K/V tiles (64 keys) double-buffered in LDS [2][64][64] (32 KiB total),
// staged with global_load_lds (T14/2-phase): linear LDS dest, XOR-swizzled
// global source, swizzled ds_read (rule 21). One barrier per K-tile.
__global__ __launch_bounds__(256, 4) void attn_kernel(const __bf16* __restrict__ qkv,
                                                      const __bf16* __restrict__ Vt,
                                                      __bf16* __restrict__ v2) {
    const int bh = blockIdx.x;
    const int b = bh >> 4, h = bh & 15;
    const int q0 = blockIdx.y * 128;
    const int tid  = threadIdx.x;
    const int lane = tid & 63;
    const int wave = tid >> 6;
    const int l31  = lane & 31;
    const int hi   = lane >> 5;          // half-wave index
    const int kx   = l31 & 7;            // row XOR key for LDS swizzle
    const size_t rs = QKV_N;
    const __bf16* base  = qkv + (size_t)b * Sq * rs + (size_t)h * (3 * HDq);
    const __bf16* vbase = Vt + (size_t)bh * HDq * Sq;

    __shared__ alignas(16) __bf16 Ks[2][64][64];   // [buf][key][d]   (swizzled)
    __shared__ alignas(16) __bf16 Vs[2][64][64];   // [buf][d][key]   (swizzled)

    // Q B-frags: lane holds Q[q=l31][d = hi*8 + j + st*16]  (QSCALE pre-folded)
    bf16x8 qb[4];
    {
        const __bf16* qr = base + (size_t)(q0 + wave * 32 + l31) * rs + hi * 8;
#pragma unroll
        for (int st = 0; st < 4; ++st) qb[st] = *(const bf16x8*)(qr + st * 16);
    }

    // Staging map: wave-issue covers 8 rows x 64 cols (1 KiB); lane ->
    // (row = base+lane/8, slot = lane&7). LDS dest is linear (base+lane*16);
    // the XOR swizzle lives in the GLOBAL source slot: slot ^ (row&7).
    const int rA = wave * 8 + (lane >> 3);          // rows 0..31
    const int rB = rA + 32;                         // rows 32..63 (same &7)
    const int sw = ((lane & 7) ^ (rA & 7)) * 8;     // pre-swizzled elem offset
    const __bf16* gK0 = base + HDq + (size_t)rA * rs + sw;
    const __bf16* gK1 = base + HDq + (size_t)rB * rs + sw;
    const __bf16* gV0 = vbase + (size_t)rA * Sq + sw;
    const __bf16* gV1 = vbase + (size_t)rB * Sq + sw;
    const int loff0 = wave * 512 + lane * 8;        // elem offsets into a buf
    const int loff1 = (4 + wave) * 512 + lane * 8;

    auto STAGE = [&](int bufi, int kt) {
        const size_t ko = (size_t)kt * rs;
        async16(gK0 + ko, &Ks[bufi][0][0] + loff0);
        async16(gK1 + ko, &Ks[bufi][0][0] + loff1);
        async16(gV0 + kt, &Vs[bufi][0][0] + loff0);
        async16(gV1 + kt, &Vs[bufi][0][0] + loff1);
    };

    floatx16 o0 = {}, o1 = {};   // O^T d-tiles 0..31 / 32..63, col q = l31
    float l_acc = 0.f;

    STAGE(0, 0);
    __syncthreads();             // compiler drains vmcnt before s_barrier

    int cur = 0;
    for (int kt = 0; kt < Sq; kt += 64, cur ^= 1) {
        if (kt + 64 < Sq) STAGE(cur ^ 1, kt + 64);  // in flight across compute

#pragma unroll
        for (int half = 0; half < 2; ++half) {
            const int key = half * 32 + l31;        // A-frag row (key&7 == kx)

            // S^T = K Q^T : 4 mfma over d (K-dim 16 each)
            floatx16 c = {};
#pragma unroll
            for (int st = 0; st < 4; ++st) {
                bf16x8 a = *(const bf16x8*)(&Ks[cur][key][((st * 2 + hi) ^ kx) * 8]);
                c = MFMA32(a, qb[st], c);
            }

            // exp2 + bf16 pack: W[m] = pack(exp(c[2m]), exp(c[2m+1]))
            // reg pairs -> key pairs: m=0..7 -> keys (0,1)(2,3)(8,9)(10,11)
            // (16,17)(18,19)(24,25)(26,27)  [+4 for hi half]
            unsigned int W[8];
#pragma unroll
            for (int m = 0; m < 8; ++m) {
                float e0 = __builtin_amdgcn_exp2f(c[2 * m]);
                float e1 = __builtin_amdgcn_exp2f(c[2 * m + 1]);
                l_acc += e0 + e1;
                union { bf16x2 v; unsigned int u; } pk;
                pk.v[0] = (__bf16)e0; pk.v[1] = (__bf16)e1;
                W[m] = pk.u;
            }

            // P^T B-frag per 16-key slice via permlane32_swap:
            // ret[0] = [a.lo|b.lo], ret[1] = [a.hi|b.hi]
            // B dwords = [s(W0,W2).0, s(W1,W3).0, s(W0,W2).1, s(W1,W3).1]
#pragma unroll
            for (int ks = 0; ks < 2; ++ks) {
                auto r0 = __builtin_amdgcn_permlane32_swap(W[ks * 4 + 0], W[ks * 4 + 2], false, false);
                auto r1 = __builtin_amdgcn_permlane32_swap(W[ks * 4 + 1], W[ks * 4 + 3], false, false);
                uintx4 bb; bb[0] = r0[0]; bb[1] = r1[0]; bb[2] = r0[1]; bb[3] = r1[1];
                bf16x8 pb = __builtin_bit_cast(bf16x8, bb);

                const int kslot = half * 4 + ks * 2 + hi;  // 16B key-slot 0..7
                bf16x8 va0 = *(const bf16x8*)(&Vs[cur][l31][(kslot ^ kx) * 8]);
                bf16x8 va1 = *(const bf16x8*)(&Vs[cur][32 + l31][(kslot ^ kx) * 8]);
                o0 = MFMA32(va0, pb, o0);
                o1 = MFMA32(va1, pb, o1);
            }
        }
        __syncthreads();  // drains stage vmcnt; protects buf reuse
    }

    // l reduction: lanes l and l^32 hold the two key-halves of the same q
    float l = l_acc + __shfl_xor(l_acc, 32);
    float rinv = 1.0f / l;

    // Epilogue. O^T C-layout: col q=l31, row d = (reg&3)+8*(reg>>2)+4*hi.
    // Quirk reshape: v2[b*2048 + h*128 + q/16][(q%16)*64 + d]
    const int q = q0 + wave * 32 + l31;
    size_t row = (size_t)b * Sq + h * 128 + (q >> 4);
    __bf16* vrow = v2 + row * Dq + (size_t)(q & 15) * 64;
#pragma unroll
    for (int gg = 0; gg < 4; ++gg) {
        bf16x4 ov;
#pragma unroll
        for (int i = 0; i < 4; ++i) ov[i] = (__bf16)(o0[gg * 4 + i] * rinv);
        *(bf16x4*)(vrow + gg * 8 + hi * 4) = ov;
#pragma unroll
        for (int i = 0; i < 4; ++i) ov[i] = (__bf16)(o1[gg * 4 + i] * rinv);
        *(bf16x4*)(vrow + 32 + gg * 8 + hi * 4) = ov;
    }
}

// ---------------------------------------------------------------------------
extern "C" void kernel_launch(void* const* d_in, const int* in_sizes, int n_in,
                              void* d_out, int out_size, void* d_ws, size_t ws_size,
                              hipStream_t stream) {
    const float* x    = (const float*)d_in[0];  // [4,2048,1024]
    const float* Wqkv = (const float*)d_in[1];  // [1024,3072]
    const float* bqkv = (const float*)d_in[2];  // [3072]
    const float* Wo   = (const float*)d_in[3];  // [1024,1024]
    const float* bo   = (const float*)d_in[4];  // [1024]
    float* out = (float*)d_out;                 // [4,2048,1024] f32

    __bf16* xb    = (__bf16*)d_ws;                        // 8192*1024
    __bf16* WqkvT = xb    + (size_t)ROWS * Dq;            // 3072*1024
    __bf16* WoT   = WqkvT + (size_t)QKV_N * Dq;           // 1024*1024
    __bf16* qkvb  = WoT   + (size_t)Dq * Dq;              // 8192*3072
    __bf16* Vt    = qkvb  + (size_t)ROWS * QKV_N;         // 64*64*2048
    __bf16* v2    = xb;                                   // alias (xb dead)

    const int nx4 = ROWS * Dq / 4;
    cvt4_kernel<<<(nx4 + 255) / 256, 256, 0, stream>>>((const float4*)x, (bf16x4*)xb, nx4);
    tcvt_kernel<<<dim3(QKV_N / 32, Dq / 32), 256, 0, stream>>>(Wqkv, WqkvT, Dq, QKV_N);
    tcvt_kernel<<<dim3(Dq / 32, Dq / 32), 256, 0, stream>>>(Wo, WoT, Dq, Dq);

    gemm_bt_kernel<2><<<dim3(QKV_N / 128, ROWS / 128), 256, 0, stream>>>(
        xb, WqkvT, bqkv, (void*)qkvb, Vt, ROWS, QKV_N, Dq);

    attn_kernel<<<dim3(Bq * Hq, Sq / 128), 256, 0, stream>>>(qkvb, Vt, v2);

    gemm_bt_kernel<1><<<dim3(Dq / 128, ROWS / 128), 256, 0, stream>>>(
        v2, WoT, bo, (void*)out, nullptr, ROWS, Dq, Dq);
}

// Round 2
// 278.649 us; speedup vs baseline: 1.0485x; 1.0485x over previous
//
#include <hip/hip_runtime.h>
#include <hip/hip_bf16.h>
#include <cstdint>

// Problem constants: B=4, S=2048, D=1024, H=16, HD=64
static constexpr int Bq  = 4;
static constexpr int Sq  = 2048;
static constexpr int Dq  = 1024;
static constexpr int Hq  = 16;
static constexpr int HDq = 64;
static constexpr int ROWS = Bq * Sq;        // 8192
static constexpr int QKV_N = 3 * Dq;        // 3072

typedef __bf16 bf16x8 __attribute__((ext_vector_type(8)));
typedef __bf16 bf16x4 __attribute__((ext_vector_type(4)));
typedef __bf16 bf16x2 __attribute__((ext_vector_type(2)));
typedef float  floatx4 __attribute__((ext_vector_type(4)));
typedef float  floatx16 __attribute__((ext_vector_type(16)));
typedef unsigned int uintx4 __attribute__((ext_vector_type(4)));

#define MFMA16(a, b, c) __builtin_amdgcn_mfma_f32_16x16x32_bf16((a), (b), (c), 0, 0, 0)
#define MFMA32(a, b, c) __builtin_amdgcn_mfma_f32_32x32x16_bf16((a), (b), (c), 0, 0, 0)

// 0.125 (1/sqrt(HD)) * log2(e): folded into q so softmax uses exp2 directly.
#define QSCALE 0.18033688011112042f

// Async global->LDS 16B copy (global_load_lds_dwordx4).
__device__ __forceinline__ void async16(const void* g, void* l) {
    __builtin_amdgcn_global_load_lds(
        (const __attribute__((address_space(1))) uint32_t*)g,
        (__attribute__((address_space(3))) uint32_t*)l, 16, 0, 0);
}

// ---------------------------------------------------------------------------
// fp32 -> bf16 elementwise convert, 4 elems/thread
__global__ __launch_bounds__(256) void cvt4_kernel(const float4* __restrict__ in,
                                                   bf16x4* __restrict__ out, int n4) {
    int i = blockIdx.x * 256 + threadIdx.x;
    if (i < n4) {
        float4 v = in[i];
        bf16x4 o;
        o[0] = (__bf16)v.x; o[1] = (__bf16)v.y; o[2] = (__bf16)v.z; o[3] = (__bf16)v.w;
        out[i] = o;
    }
}

// fp32 [K,N] -> bf16 transposed [N,K], LDS-tiled 32x32 for coalescing
__global__ __launch_bounds__(256) void tcvt_kernel(const float* __restrict__ in,
                                                   __bf16* __restrict__ out, int K, int N) {
    __shared__ float t[32][33];
    int n0 = blockIdx.x * 32, k0 = blockIdx.y * 32;
    int c = threadIdx.x & 31, r0 = threadIdx.x >> 5;
#pragma unroll
    for (int rr = 0; rr < 32; rr += 8)
        t[r0 + rr][c] = in[(size_t)(k0 + r0 + rr) * N + n0 + c];
    __syncthreads();
#pragma unroll
    for (int rr = 0; rr < 32; rr += 8)
        out[(size_t)(n0 + r0 + rr) * K + k0 + c] = (__bf16)t[c][r0 + rr];
}

// ---------------------------------------------------------------------------
// C[M,N] = A[M,K] @ BT[N,K]^T + bias[N]  (m97-ladder structure).
// MODE 1: f32 C out.  MODE 2 (QKV): q-chunks scaled by QSCALE -> bf16 C;
// k-chunks -> bf16 C; v-chunks -> transposed Vt[b][h][d][s].
template <int MODE>
__global__ __launch_bounds__(256) void gemm_bt_kernel(const __bf16* __restrict__ A,
                                                      const __bf16* __restrict__ BT,
                                                      const float* __restrict__ bias,
                                                      void* __restrict__ Cout,
                                                      __bf16* __restrict__ Vt,
                                                      int M, int N, int K) {
    __shared__ __bf16 As[128 * 32];
    __shared__ __bf16 Bs[128 * 32];

    const int t = threadIdx.x;
    const int lane = t & 63;
    const int wave = t >> 6;
    const int wm = wave & 1, wn = wave >> 1;
    const int l15 = lane & 15;
    const int kg = (lane >> 4) * 8;

    const int m0 = blockIdx.y * 128;
    const int n0 = blockIdx.x * 128;

    const int srow = t >> 2;
    const int scol = (t & 3) * 8;
    const __bf16* ag = A  + (size_t)(m0 + srow) * K + scol;
    const __bf16* bg = BT + (size_t)(n0 + srow) * K + scol;
    __bf16* al = As + t * 8;
    __bf16* bl = Bs + t * 8;

    floatx4 acc[4][4] = {};

    for (int k0 = 0; k0 < K; k0 += 32) {
        __syncthreads();
        async16(ag + k0,                    al);
        async16(ag + (size_t)64 * K + k0,   al + 2048);
        async16(bg + k0,                    bl);
        async16(bg + (size_t)64 * K + k0,   bl + 2048);
        __syncthreads();

        bf16x8 af[4], bfr[4];
#pragma unroll
        for (int mi = 0; mi < 4; ++mi)
            af[mi] = *(const bf16x8*)(As + (wm * 64 + mi * 16 + l15) * 32 + kg);
#pragma unroll
        for (int ni = 0; ni < 4; ++ni)
            bfr[ni] = *(const bf16x8*)(Bs + (wn * 64 + ni * 16 + l15) * 32 + kg);
#pragma unroll
        for (int mi = 0; mi < 4; ++mi)
#pragma unroll
            for (int ni = 0; ni < 4; ++ni)
                acc[mi][ni] = MFMA16(af[mi], bfr[ni], acc[mi][ni]);
    }

    // C/D layout: col = lane&15, row = (lane>>4)*4 + reg   [verified m89/m91]
    const int r0 = (lane >> 4) * 4;
    const int wn0 = n0 + wn * 64;

    if (MODE == 2 && (wn0 % 192) == 128) {
        // v-chunk -> Vt[b][h][d][s]; lane's 4 consecutive rows = 8B store
#pragma unroll
        for (int ni = 0; ni < 4; ++ni) {
            int col = wn0 + ni * 16 + l15;
            float bv = bias[col];
            int h = col / 192;
            int d = col - h * 192 - 128;
#pragma unroll
            for (int mi = 0; mi < 4; ++mi) {
                int row = m0 + wm * 64 + mi * 16 + r0;
                int b = row >> 11, s = row & 2047;
                bf16x4 vv;
#pragma unroll
                for (int i = 0; i < 4; ++i) vv[i] = (__bf16)(acc[mi][ni][i] + bv);
                *(bf16x4*)(Vt + ((size_t)(b * Hq + h) * HDq + d) * Sq + s) = vv;
            }
        }
    } else {
        // wave-uniform q-scale for MODE 2 q-chunks (wn0%192==0)
        const float sc = (MODE == 2 && (wn0 % 192) == 0) ? QSCALE : 1.0f;
#pragma unroll
        for (int ni = 0; ni < 4; ++ni) {
            int col = wn0 + ni * 16 + l15;
            float bv = bias[col];
#pragma unroll
            for (int mi = 0; mi < 4; ++mi) {
#pragma unroll
                for (int i = 0; i < 4; ++i) {
                    int row = m0 + wm * 64 + mi * 16 + r0 + i;
                    float v = (acc[mi][ni][i] + bv) * sc;
                    size_t off = (size_t)row * N + col;
                    if (MODE == 1) ((float*)Cout)[off] = v;
                    else           ((__bf16*)Cout)[off] = (__bf16)v;
                }
            }
        }
    }
}

// ---------------------------------------------------------------------------
// Flash attention, 32x32-MFMA transposed compute (S^T = K Q^T, O^T = V^T P^T),
// max-free softmax (q pre-scaled by 0.125*log2e -> p = exp2(s)).
//
// R2 change: wave q-tile 32 -> 64 (two register-resident Q B-frags / P
// B-frags per LDS A-frag read). LDS reads per MFMA drop 1.0 -> 0.5 -- the
// LDS pipe was the widest pipe at R1 (16 b128 x 12cyc = 192 cyc/wave-iter
// vs 128 MFMA cyc). Block = one (b,h) x 256 q rows; 4 waves; wave owns 64 q.
// Grid bh-major (gridDim.x=64, 0 mod 8) -> all q-blocks of a (b,h) on one
// XCD (T1; FETCH 143->27MB at R1).
//
// S^T 32x32 C-layout: col=q(lane&31), row=key=(reg&3)+8*(reg>>2)+4*(lane>>5).
// P regrouping for PV's B-frag is 2 permlane32_swap per 16-key slice (T12).
// l_acc kept in independent partial sums (no serial fp-add chain).
//
// K/V tiles (64 keys) double-buffered in LDS [2][64][64] (32 KiB), staged
// with global_load_lds: linear LDS dest, XOR-swizzled global source,
// swizzled ds_read (rule 21). One barrier per K-tile.
__global__ __launch_bounds__(256, 2) void attn_kernel(const __bf16* __restrict__ qkv,
                                                      const __bf16* __restrict__ Vt,
                                                      __bf16* __restrict__ v2) {
    const int bh = blockIdx.x;
    const int b = bh >> 4, h = bh & 15;
    const int q0 = blockIdx.y * 256;
    const int tid  = threadIdx.x;
    const int lane = tid & 63;
    const int wave = tid >> 6;
    const int l31  = lane & 31;
    const int hi   = lane >> 5;          // half-wave index
    const int kx   = l31 & 7;            // row XOR key for LDS swizzle
    const size_t rs = QKV_N;
    const __bf16* base  = qkv + (size_t)b * Sq * rs + (size_t)h * (3 * HDq);
    const __bf16* vbase = Vt + (size_t)bh * HDq * Sq;

    __shared__ alignas(16) __bf16 Ks[2][64][64];   // [buf][key][d]   (swizzled)
    __shared__ alignas(16) __bf16 Vs[2][64][64];   // [buf][d][key]   (swizzled)

    // Q B-frags, two 32-q groups: lane holds Q[q][d = hi*8 + j + st*16]
    bf16x8 qb[2][4];
#pragma unroll
    for (int qg = 0; qg < 2; ++qg) {
        const __bf16* qr = base + (size_t)(q0 + wave * 64 + qg * 32 + l31) * rs + hi * 8;
#pragma unroll
        for (int st = 0; st < 4; ++st) qb[qg][st] = *(const bf16x8*)(qr + st * 16);
    }

    // Staging map: wave-issue covers 8 rows x 64 cols (1 KiB); lane ->
    // (row = base+lane/8, slot = lane&7). LDS dest is linear (base+lane*16);
    // the XOR swizzle lives in the GLOBAL source slot: slot ^ (row&7).
    const int rA = wave * 8 + (lane >> 3);          // rows 0..31
    const int rB = rA + 32;                         // rows 32..63 (same &7)
    const int sw = ((lane & 7) ^ (rA & 7)) * 8;     // pre-swizzled elem offset
    const __bf16* gK0 = base + HDq + (size_t)rA * rs + sw;
    const __bf16* gK1 = base + HDq + (size_t)rB * rs + sw;
    const __bf16* gV0 = vbase + (size_t)rA * Sq + sw;
    const __bf16* gV1 = vbase + (size_t)rB * Sq + sw;
    const int loff0 = wave * 512 + lane * 8;        // elem offsets into a buf
    const int loff1 = (4 + wave) * 512 + lane * 8;

    auto STAGE = [&](int bufi, int kt) {
        const size_t ko = (size_t)kt * rs;
        async16(gK0 + ko, &Ks[bufi][0][0] + loff0);
        async16(gK1 + ko, &Ks[bufi][0][0] + loff1);
        async16(gV0 + kt, &Vs[bufi][0][0] + loff0);
        async16(gV1 + kt, &Vs[bufi][0][0] + loff1);
    };

    // exp2 + bf16 pack + permlane regroup: c (16 scores) -> 2 PV B-frags.
    // W[m] = pack(exp2 c[2m], exp2 c[2m+1]); B dwords per 16-key slice =
    // [s(W0,W2).0, s(W1,W3).0, s(W0,W2).1, s(W1,W3).1].
    auto softmax_pb = [&](const floatx16& c, float& la, bf16x8* pb) {
        unsigned int W[8];
        float s0 = 0.f, s1 = 0.f;
#pragma unroll
        for (int m = 0; m < 8; ++m) {
            float e0 = __builtin_amdgcn_exp2f(c[2 * m]);
            float e1 = __builtin_amdgcn_exp2f(c[2 * m + 1]);
            s0 += e0; s1 += e1;              // two independent add chains
            union { bf16x2 v; unsigned int u; } pk;
            pk.v[0] = (__bf16)e0; pk.v[1] = (__bf16)e1;
            W[m] = pk.u;
        }
        la += s0 + s1;
#pragma unroll
        for (int ks = 0; ks < 2; ++ks) {
            auto r0 = __builtin_amdgcn_permlane32_swap(W[ks * 4 + 0], W[ks * 4 + 2], false, false);
            auto r1 = __builtin_amdgcn_permlane32_swap(W[ks * 4 + 1], W[ks * 4 + 3], false, false);
            uintx4 bb; bb[0] = r0[0]; bb[1] = r1[0]; bb[2] = r0[1]; bb[3] = r1[1];
            pb[ks] = __builtin_bit_cast(bf16x8, bb);
        }
    };

    floatx16 o[2][2] = {};   // [qg][d-half]: O^T d rows 0..31 / 32..63, col q
    float la0 = 0.f, la1 = 0.f;

    STAGE(0, 0);
    __syncthreads();             // compiler drains vmcnt before s_barrier

    int cur = 0;
    for (int kt = 0; kt < Sq; kt += 64, cur ^= 1) {
        if (kt + 64 < Sq) STAGE(cur ^ 1, kt + 64);  // in flight across compute

#pragma unroll
        for (int half = 0; half < 2; ++half) {
            const int key = half * 32 + l31;        // A-frag row (key&7 == kx)

            // S^T = K Q^T : each K A-frag read feeds both q-groups
            floatx16 c0 = {}, c1 = {};
#pragma unroll
            for (int st = 0; st < 4; ++st) {
                bf16x8 a = *(const bf16x8*)(&Ks[cur][key][((st * 2 + hi) ^ kx) * 8]);
                c0 = MFMA32(a, qb[0][st], c0);
                c1 = MFMA32(a, qb[1][st], c1);
            }

            bf16x8 pb0[2], pb1[2];
            softmax_pb(c0, la0, pb0);
            softmax_pb(c1, la1, pb1);

            // O^T += V^T P^T : each V A-frag read feeds both q-groups
#pragma unroll
            for (int ks = 0; ks < 2; ++ks) {
                const int kslot = half * 4 + ks * 2 + hi;  // 16B key-slot 0..7
                bf16x8 va0 = *(const bf16x8*)(&Vs[cur][l31][(kslot ^ kx) * 8]);
                bf16x8 va1 = *(const bf16x8*)(&Vs[cur][32 + l31][(kslot ^ kx) * 8]);
                o[0][0] = MFMA32(va0, pb0[ks], o[0][0]);
                o[0][1] = MFMA32(va1, pb0[ks], o[0][1]);
                o[1][0] = MFMA32(va0, pb1[ks], o[1][0]);
                o[1][1] = MFMA32(va1, pb1[ks], o[1][1]);
            }
        }
        __syncthreads();  // drains stage vmcnt; protects buf reuse
    }

    // l reduction: lanes l and l^32 hold the two key-halves of the same q.
    // Epilogue per q-group. O^T C-layout: col q=l31, row d=(reg&3)+8*(reg>>2)+4*hi.
    // Quirk reshape: v2[b*2048 + h*128 + q/16][(q%16)*64 + d]
#pragma unroll
    for (int qg = 0; qg < 2; ++qg) {
        float lsum = qg ? la1 : la0;
        float l = lsum + __shfl_xor(lsum, 32);
        float rinv = 1.0f / l;
        const int q = q0 + wave * 64 + qg * 32 + l31;
        size_t row = (size_t)b * Sq + h * 128 + (q >> 4);
        __bf16* vrow = v2 + row * Dq + (size_t)(q & 15) * 64;
#pragma unroll
        for (int gg = 0; gg < 4; ++gg) {
            bf16x4 ov;
#pragma unroll
            for (int i = 0; i < 4; ++i) ov[i] = (__bf16)(o[qg][0][gg * 4 + i] * rinv);
            *(bf16x4*)(vrow + gg * 8 + hi * 4) = ov;
#pragma unroll
            for (int i = 0; i < 4; ++i) ov[i] = (__bf16)(o[qg][1][gg * 4 + i] * rinv);
            *(bf16x4*)(vrow + 32 + gg * 8 + hi * 4) = ov;
        }
    }
}

// ---------------------------------------------------------------------------
extern "C" void kernel_launch(void* const* d_in, const int* in_sizes, int n_in,
                              void* d_out, int out_size, void* d_ws, size_t ws_size,
                              hipStream_t stream) {
    const float* x    = (const float*)d_in[0];  // [4,2048,1024]
    const float* Wqkv = (const float*)d_in[1];  // [1024,3072]
    const float* bqkv = (const float*)d_in[2];  // [3072]
    const float* Wo   = (const float*)d_in[3];  // [1024,1024]
    const float* bo   = (const float*)d_in[4];  // [1024]
    float* out = (float*)d_out;                 // [4,2048,1024] f32

    __bf16* xb    = (__bf16*)d_ws;                        // 8192*1024
    __bf16* WqkvT = xb    + (size_t)ROWS * Dq;            // 3072*1024
    __bf16* WoT   = WqkvT + (size_t)QKV_N * Dq;           // 1024*1024
    __bf16* qkvb  = WoT   + (size_t)Dq * Dq;              // 8192*3072
    __bf16* Vt    = qkvb  + (size_t)ROWS * QKV_N;         // 64*64*2048
    __bf16* v2    = xb;                                   // alias (xb dead)

    const int nx4 = ROWS * Dq / 4;
    cvt4_kernel<<<(nx4 + 255) / 256, 256, 0, stream>>>((const float4*)x, (bf16x4*)xb, nx4);
    tcvt_kernel<<<dim3(QKV_N / 32, Dq / 32), 256, 0, stream>>>(Wqkv, WqkvT, Dq, QKV_N);
    tcvt_kernel<<<dim3(Dq / 32, Dq / 32), 256, 0, stream>>>(Wo, WoT, Dq, Dq);

    gemm_bt_kernel<2><<<dim3(QKV_N / 128, ROWS / 128), 256, 0, stream>>>(
        xb, WqkvT, bqkv, (void*)qkvb, Vt, ROWS, QKV_N, Dq);

    attn_kernel<<<dim3(Bq * Hq, Sq / 256), 256, 0, stream>>>(qkvb, Vt, v2);

    gemm_bt_kernel<1><<<dim3(Dq / 128, ROWS / 128), 256, 0, stream>>>(
        v2, WoT, bo, (void*)out, nullptr, ROWS, Dq, Dq);
}